// Round 4
// baseline (86.300 us; speedup 1.0000x reference)
//
#include <hip/hip_runtime.h>
#include <hip/hip_bf16.h>

// GraphConv: out[b,n,f] = relu( sum_{k,d} x[b, nbr[n,k], d] * W[k,d,f] + bias[f] )
// B=4, N=50000, D=32, K=16, F=32.  M = B*N = 200000 rows, contraction = 512.
// Strategy: bf16 MFMA (16x16x32). A gathered per-lane straight from global
// (lane layout == A fragment layout), W staged once per block into LDS
// transposed [k][f][d] (d padded to 40 -> conflict-light ds_read_b128).

typedef __attribute__((ext_vector_type(8))) short bf16x8;
typedef __attribute__((ext_vector_type(4))) float f32x4;

constexpr int B_ = 4, N_ = 50000, D_ = 32, K_ = 16, F_ = 32;
constexpr int M_ = B_ * N_;                      // 200000
constexpr int ROWS_PER_WAVE = 16;
constexpr int WAVES = 4;
constexpr int ROWS_PER_BLOCK = ROWS_PER_WAVE * WAVES;  // 64
constexpr int DPAD = 40;                         // 80B row stride in LDS

__device__ __forceinline__ short f2bf_rne(float f) {
    union { float f; unsigned u; } v; v.f = f;
    unsigned r = v.u + 0x7FFFu + ((v.u >> 16) & 1u);
    return (short)(r >> 16);
}

__global__ __launch_bounds__(256) void graphconv_mfma(
    const float* __restrict__ x,
    const int*   __restrict__ nbr,
    const float* __restrict__ kern,
    const float* __restrict__ bias,
    float*       __restrict__ out)
{
    __shared__ __align__(16) short klds[K_][F_][DPAD];   // 40 KB

    // ---- stage W -> LDS, bf16, transposed to [k][f][d] (one time) ----
    for (int e = threadIdx.x; e < K_ * D_ * F_; e += 256) {
        int kk = e >> 10;          // / (D_*F_)
        int d  = (e >> 5) & 31;
        int f  = e & 31;
        klds[kk][f][d] = f2bf_rne(kern[e]);
    }

    // ---- detect int64-pushed-as-int32 neighbor buffer (hedge) ----
    // If neighbors were pushed as int64, every odd dword is a zero high word
    // (indices < 50000). For int32 data these are 8 random indices; the
    // all-zero false positive probability is ~ (2e-5)^8.
    const bool is64 = (nbr[1] | nbr[3] | nbr[5] | nbr[7] |
                       nbr[9] | nbr[11] | nbr[13] | nbr[15]) == 0;
    const int istride = is64 ? 2 : 1;

    __syncthreads();

    const int lane = threadIdx.x & 63;
    const int wid  = threadIdx.x >> 6;
    const int m0   = blockIdx.x * ROWS_PER_BLOCK + wid * ROWS_PER_WAVE;

    const int r     = lane & 15;   // A-row / B-col this lane serves
    const int chunk = lane >> 4;   // k-chunk (group of 8 d's)
    const int m     = m0 + r;
    const int b     = m / N_;
    const int n     = m - b * N_;

    // preload this row's 16 neighbor indices (redundant x4 across chunks; cached)
    int idxs[K_];
#pragma unroll
    for (int kk = 0; kk < K_; ++kk)
        idxs[kk] = nbr[(size_t)(n * K_ + kk) * istride];

    const float* xbase = x + (size_t)b * (N_ * D_) + chunk * 8;
    const short* bcol0 = &klds[0][r][chunk * 8];        // f = r
    const short* bcol1 = &klds[0][16 + r][chunk * 8];   // f = 16 + r
    constexpr int KSTRIDE = F_ * DPAD;                  // shorts per k-slab

    f32x4 acc0 = {0.f, 0.f, 0.f, 0.f};
    f32x4 acc1 = {0.f, 0.f, 0.f, 0.f};

#pragma unroll
    for (int kk = 0; kk < K_; ++kk) {
        const float* xr = xbase + (size_t)idxs[kk] * D_;
        f32x4 xa = *reinterpret_cast<const f32x4*>(xr);
        f32x4 xb = *reinterpret_cast<const f32x4*>(xr + 4);

        unsigned p0, p1, p2, p3;
        asm("v_cvt_pk_bf16_f32 %0, %1, %2" : "=v"(p0) : "v"(xa.x), "v"(xa.y));
        asm("v_cvt_pk_bf16_f32 %0, %1, %2" : "=v"(p1) : "v"(xa.z), "v"(xa.w));
        asm("v_cvt_pk_bf16_f32 %0, %1, %2" : "=v"(p2) : "v"(xb.x), "v"(xb.y));
        asm("v_cvt_pk_bf16_f32 %0, %1, %2" : "=v"(p3) : "v"(xb.z), "v"(xb.w));
        union { unsigned u[4]; bf16x8 v; } af;
        af.u[0] = p0; af.u[1] = p1; af.u[2] = p2; af.u[3] = p3;

        bf16x8 b0 = *reinterpret_cast<const bf16x8*>(bcol0 + kk * KSTRIDE);
        bf16x8 b1 = *reinterpret_cast<const bf16x8*>(bcol1 + kk * KSTRIDE);

        acc0 = __builtin_amdgcn_mfma_f32_16x16x32_bf16(af.v, b0, acc0, 0, 0, 0);
        acc1 = __builtin_amdgcn_mfma_f32_16x16x32_bf16(af.v, b1, acc1, 0, 0, 0);
    }

    // ---- epilogue: C layout col=lane&15, row=(lane>>4)*4+reg ----
    const float bv0 = bias[r];
    const float bv1 = bias[16 + r];
    const int rowbase = m0 + (lane >> 4) * 4;
#pragma unroll
    for (int j = 0; j < 4; ++j) {
        const size_t o = (size_t)(rowbase + j) * F_;
        float v0 = acc0[j] + bv0;
        float v1 = acc1[j] + bv1;
        out[o + r]      = v0 > 0.f ? v0 : 0.f;
        out[o + 16 + r] = v1 > 0.f ? v1 : 0.f;
    }
}

extern "C" void kernel_launch(void* const* d_in, const int* in_sizes, int n_in,
                              void* d_out, int out_size, void* d_ws, size_t ws_size,
                              hipStream_t stream) {
    const float* x    = (const float*)d_in[0];
    const int*   nbr  = (const int*)d_in[1];
    const float* kern = (const float*)d_in[2];
    const float* bias = (const float*)d_in[3];
    float* out = (float*)d_out;

    dim3 grid(M_ / ROWS_PER_BLOCK);   // 3125, exact
    graphconv_mfma<<<grid, 256, 0, stream>>>(x, nbr, kern, bias, out);
}